// Round 1
// baseline (1406.021 us; speedup 1.0000x reference)
//
#include <hip/hip_runtime.h>

#define NB   32
#define CB   256
#define HB   56
#define WB   56
#define HWB  3136   // 56*56
#define KKC  1152   // 128*9, conv K per group

// ---------------------------------------------------------------------------
// K1: t4[n*C+a][e] = (sum_hw x[n*C+a][hw] * p1[hw][e]) * p4[a][e]
// GEMM M=8192, K=3136, N=256. 64x64 tile, BK=16, 4x4 per thread.
// ---------------------------------------------------------------------------
__global__ __launch_bounds__(256) void k_gemm_t4(
    const float* __restrict__ x, const float* __restrict__ p1,
    const float* __restrict__ p4, float* __restrict__ t4)
{
    const int tid   = threadIdx.x;
    const int tileM = blockIdx.y * 64;
    const int tileN = blockIdx.x * 64;
    __shared__ float As[16][68];
    __shared__ float Bs[16][68];
    float acc[4][4] = {};
    const int tx = tid & 15, ty = tid >> 4;
    const int mA = tid >> 2, kA = (tid & 3) * 4;          // A: 64 rows x 4 k-quads
    const int nB = (tid & 15) * 4, kB = tid >> 4;         // B: 16 k x 16 n-quads

    const float* xrow = x + (size_t)(tileM + mA) * HWB + kA;
    const float* brow = p1 + (size_t)kB * 256 + tileN + nB;

    for (int k0 = 0; k0 < HWB; k0 += 16) {
        float4 av = *(const float4*)(xrow + k0);
        float4 bv = *(const float4*)(brow + (size_t)k0 * 256);
        As[kA + 0][mA] = av.x;
        As[kA + 1][mA] = av.y;
        As[kA + 2][mA] = av.z;
        As[kA + 3][mA] = av.w;
        *(float4*)&Bs[kB][nB] = bv;
        __syncthreads();
#pragma unroll
        for (int k = 0; k < 16; ++k) {
            float4 a = *(const float4*)&As[k][ty * 4];
            float4 b = *(const float4*)&Bs[k][tx * 4];
            float aa[4] = {a.x, a.y, a.z, a.w};
            float bb[4] = {b.x, b.y, b.z, b.w};
#pragma unroll
            for (int i = 0; i < 4; ++i)
#pragma unroll
                for (int j = 0; j < 4; ++j) acc[i][j] += aa[i] * bb[j];
        }
        __syncthreads();
    }
#pragma unroll
    for (int i = 0; i < 4; ++i) {
        const int row = tileM + ty * 4 + i;
        const int col = tileN + tx * 4;
        float4 sc = *(const float4*)&p4[(size_t)(row & 255) * 256 + col];
        float4 o;
        o.x = acc[i][0] * sc.x;
        o.y = acc[i][1] * sc.y;
        o.z = acc[i][2] * sc.z;
        o.w = acc[i][3] * sc.w;
        *(float4*)&t4[(size_t)row * 256 + col] = o;
    }
}

// ---------------------------------------------------------------------------
// K2: t5[row] = sum_b t4[row][b] * p5[b]   (one wave per row)
// ---------------------------------------------------------------------------
__global__ __launch_bounds__(256) void k_t5(
    const float* __restrict__ t4, const float* __restrict__ p5,
    float* __restrict__ t5)
{
    const int wave = blockIdx.x * 4 + (threadIdx.x >> 6);
    const int lane = threadIdx.x & 63;
    float4 a = *(const float4*)&t4[(size_t)wave * 256 + lane * 4];
    float4 b = *(const float4*)&p5[lane * 4];
    float sum = a.x * b.x + a.y * b.y + a.z * b.z + a.w * b.w;
#pragma unroll
    for (int off = 32; off > 0; off >>= 1) sum += __shfl_down(sum, off);
    if (lane == 0) t5[wave] = sum;
}

// ---------------------------------------------------------------------------
// K3: grouped 3x3 conv as implicit GEMM per (n,g):
//     t3[o][s] = sum_k W[o][k] * Im[k][s],  k=(ci,ky,kx), K=1152
// 64x64 tile, BK=16, gather for the Im tile with LDS-cached (off,dy,dx) table.
// ---------------------------------------------------------------------------
__global__ __launch_bounds__(256) void k_conv(
    const float* __restrict__ x, const float* __restrict__ w,
    float* __restrict__ t3)
{
    const int tid   = threadIdx.x;
    const int n     = blockIdx.z >> 1, g = blockIdx.z & 1;
    const int tileM = blockIdx.y * 64;
    const int tileS = blockIdx.x * 64;
    __shared__ float As[16][68];
    __shared__ float Bs[16][68];
    __shared__ int offs[KKC];
    __shared__ signed char dys[KKC], dxs[KKC];
    for (int k = tid; k < KKC; k += 256) {
        int ci = k / 9;
        int t  = k - ci * 9;
        int dy = t / 3 - 1;
        int dx = t - (t / 3) * 3 - 1;
        offs[k] = ci * HWB + dy * WB + dx;
        dys[k] = (signed char)dy;
        dxs[k] = (signed char)dx;
    }
    __syncthreads();

    float acc[4][4] = {};
    const int tx = tid & 15, ty = tid >> 4;
    const int mA = tid >> 2, kA = (tid & 3) * 4;
    const int sb = tid & 63, kb = tid >> 6;
    const float* xb = x + ((size_t)n * CB + g * 128) * HWB;
    const float* wb = w + (size_t)(g * 128 + tileM + mA) * KKC + kA;
    const int s_glob = tileS + sb;
    const int yy = s_glob / WB;
    const int xx = s_glob - yy * WB;

    for (int k0 = 0; k0 < KKC; k0 += 16) {
        float4 av = *(const float4*)(wb + k0);
#pragma unroll
        for (int p = 0; p < 4; ++p) {
            const int k  = k0 + kb + p * 4;
            const int iy = yy + dys[k];
            const int ix = xx + dxs[k];
            float v = 0.f;
            if ((unsigned)iy < (unsigned)HB && (unsigned)ix < (unsigned)WB)
                v = xb[offs[k] + s_glob];
            Bs[kb + p * 4][sb] = v;
        }
        As[kA + 0][mA] = av.x;
        As[kA + 1][mA] = av.y;
        As[kA + 2][mA] = av.z;
        As[kA + 3][mA] = av.w;
        __syncthreads();
#pragma unroll
        for (int k = 0; k < 16; ++k) {
            float4 a = *(const float4*)&As[k][ty * 4];
            float4 b = *(const float4*)&Bs[k][tx * 4];
            float aa[4] = {a.x, a.y, a.z, a.w};
            float bb[4] = {b.x, b.y, b.z, b.w};
#pragma unroll
            for (int i = 0; i < 4; ++i)
#pragma unroll
                for (int j = 0; j < 4; ++j) acc[i][j] += aa[i] * bb[j];
        }
        __syncthreads();
    }
    float* t3b = t3 + ((size_t)n * CB + g * 128 + tileM) * HWB + tileS;
#pragma unroll
    for (int i = 0; i < 4; ++i) {
        float4 o;
        o.x = acc[i][0]; o.y = acc[i][1]; o.z = acc[i][2]; o.w = acc[i][3];
        *(float4*)&t3b[(size_t)(ty * 4 + i) * HWB + tx * 4] = o;
    }
}

// ---------------------------------------------------------------------------
// K4a: t7[n][s] = (sum_c t5[n][c] * x[n][c][s]) / 16
// ---------------------------------------------------------------------------
__global__ __launch_bounds__(256) void k_t7(
    const float* __restrict__ x, const float* __restrict__ t5,
    float* __restrict__ t7)
{
    __shared__ float s5[256];
    const int n = blockIdx.y;
    s5[threadIdx.x] = t5[n * 256 + threadIdx.x];
    __syncthreads();
    const int s = blockIdx.x * 256 + threadIdx.x;
    if (s >= HWB) return;
    const float* xb = x + (size_t)n * CB * HWB + s;
    float sum = 0.f;
#pragma unroll 8
    for (int c = 0; c < 256; ++c) sum += s5[c] * xb[(size_t)c * HWB];
    t7[n * HWB + s] = sum * 0.0625f;
}

// ---------------------------------------------------------------------------
// K4b: out[n][a][s] = (sum_b t4[n][a][b] * t3[n][b][s]) / 16 + t7[n][s]
// Batched GEMM M=256, K=256, N=3136 per n.
// ---------------------------------------------------------------------------
__global__ __launch_bounds__(256) void k_gemm_out(
    const float* __restrict__ t4, const float* __restrict__ t3,
    const float* __restrict__ t7, float* __restrict__ out)
{
    const int tid   = threadIdx.x;
    const int n     = blockIdx.z;
    const int tileM = blockIdx.y * 64;
    const int tileS = blockIdx.x * 64;
    __shared__ float As[16][68];
    __shared__ float Bs[16][68];
    float acc[4][4] = {};
    const int tx = tid & 15, ty = tid >> 4;
    const int mA = tid >> 2, kA = (tid & 3) * 4;
    const int nB = (tid & 15) * 4, kB = tid >> 4;

    const float* t4n = t4 + (size_t)n * 256 * 256 + (size_t)(tileM + mA) * 256 + kA;
    const float* t3n = t3 + (size_t)n * CB * HWB + (size_t)kB * HWB + tileS + nB;

    for (int k0 = 0; k0 < 256; k0 += 16) {
        float4 av = *(const float4*)(t4n + k0);
        float4 bv = *(const float4*)(t3n + (size_t)k0 * HWB);
        As[kA + 0][mA] = av.x;
        As[kA + 1][mA] = av.y;
        As[kA + 2][mA] = av.z;
        As[kA + 3][mA] = av.w;
        *(float4*)&Bs[kB][nB] = bv;
        __syncthreads();
#pragma unroll
        for (int k = 0; k < 16; ++k) {
            float4 a = *(const float4*)&As[k][ty * 4];
            float4 b = *(const float4*)&Bs[k][tx * 4];
            float aa[4] = {a.x, a.y, a.z, a.w};
            float bb[4] = {b.x, b.y, b.z, b.w};
#pragma unroll
            for (int i = 0; i < 4; ++i)
#pragma unroll
                for (int j = 0; j < 4; ++j) acc[i][j] += aa[i] * bb[j];
        }
        __syncthreads();
    }
    const float* t7n = t7 + (size_t)n * HWB + tileS;
    float* outb = out + ((size_t)n * CB + tileM) * HWB + tileS;
    float4 t7v = *(const float4*)&t7n[tx * 4];
#pragma unroll
    for (int i = 0; i < 4; ++i) {
        float4 o;
        o.x = acc[i][0] * 0.0625f + t7v.x;
        o.y = acc[i][1] * 0.0625f + t7v.y;
        o.z = acc[i][2] * 0.0625f + t7v.z;
        o.w = acc[i][3] * 0.0625f + t7v.w;
        *(float4*)&outb[(size_t)(ty * 4 + i) * HWB + tx * 4] = o;
    }
}

extern "C" void kernel_launch(void* const* d_in, const int* in_sizes, int n_in,
                              void* d_out, int out_size, void* d_ws, size_t ws_size,
                              hipStream_t stream) {
    const float* x  = (const float*)d_in[0];   // [32,256,56,56]
    const float* p1 = (const float*)d_in[1];   // [56,56,256,1]
    const float* cw = (const float*)d_in[2];   // [256,128,3,3]
    const float* p4 = (const float*)d_in[3];   // [1,256,256]
    const float* p5 = (const float*)d_in[4];   // [256,1]
    float* out = (float*)d_out;                // [32,256,56,56]

    float* t4 = (float*)d_ws;                          // 8192*256
    float* t3 = t4 + (size_t)8192 * 256;               // 32*256*3136
    float* t5 = t3 + (size_t)32 * 256 * 3136;          // 8192
    float* t7 = t5 + 8192;                             // 32*3136

    k_gemm_t4<<<dim3(4, 128), 256, 0, stream>>>(x, p1, p4, t4);
    k_t5<<<dim3(2048), 256, 0, stream>>>(t4, p5, t5);
    k_conv<<<dim3(49, 2, 64), 256, 0, stream>>>(x, cw, t3);
    k_t7<<<dim3(13, 32), 256, 0, stream>>>(x, t5, t7);
    k_gemm_out<<<dim3(49, 4, 32), 256, 0, stream>>>(t4, t3, t7, out);
}

// Round 2
// 454.022 us; speedup vs baseline: 3.0968x; 3.0968x over previous
//
#include <hip/hip_runtime.h>

#define HWB   3136
#define HWPAD 3200

typedef __attribute__((ext_vector_type(8))) short bf16x8;
typedef __attribute__((ext_vector_type(4))) float f32x4;

__device__ __forceinline__ unsigned short f2bf(float f) {
    unsigned u = __float_as_uint(f);
    unsigned r = (u + 0x7fffu + ((u >> 16) & 1u)) >> 16;
    return (unsigned short)r;
}
__device__ __forceinline__ float bf2f(unsigned short h) {
    return __uint_as_float(((unsigned)h) << 16);
}
__device__ __forceinline__ void gl_lds16(const void* g, void* l) {
    __builtin_amdgcn_global_load_lds(
        (const __attribute__((address_space(1))) void*)g,
        (__attribute__((address_space(3))) void*)l, 16, 0, 0);
}

// ---------------------------------------------------------------------------
// Prep A: x [32][256][3136] f32 -> x_t [32][3136][256] bf16 (channels-last)
// ---------------------------------------------------------------------------
__global__ __launch_bounds__(256) void k_prep_xt(
    const float* __restrict__ x, unsigned short* __restrict__ xt)
{
    __shared__ unsigned short tile[32][33];
    const int n = blockIdx.z, c0 = blockIdx.y * 32, s0 = blockIdx.x * 32;
    const int lx = threadIdx.x & 31, ly = threadIdx.x >> 5;
    const float* xb = x + ((size_t)(n * 256 + c0)) * HWB + s0;
#pragma unroll
    for (int it = 0; it < 4; ++it) {
        int lc = ly + it * 8;
        tile[lc][lx] = f2bf(xb[(size_t)lc * HWB + lx]);
    }
    __syncthreads();
    unsigned short* ob = xt + ((size_t)n * HWB + s0) * 256 + c0;
#pragma unroll
    for (int it = 0; it < 4; ++it) {
        int ls = ly + it * 8;
        ob[(size_t)ls * 256 + lx] = tile[lx][ls];
    }
}

// ---------------------------------------------------------------------------
// Prep B: p1 [3136][256] f32 -> p1t [256][3136] bf16
// ---------------------------------------------------------------------------
__global__ __launch_bounds__(256) void k_prep_p1t(
    const float* __restrict__ p1, unsigned short* __restrict__ p1t)
{
    __shared__ unsigned short tile[32][33];
    const int e0 = blockIdx.y * 32, h0 = blockIdx.x * 32;
    const int lx = threadIdx.x & 31, ly = threadIdx.x >> 5;
#pragma unroll
    for (int it = 0; it < 4; ++it) {
        int lh = ly + it * 8;
        tile[lh][lx] = f2bf(p1[(size_t)(h0 + lh) * 256 + e0 + lx]);
    }
    __syncthreads();
#pragma unroll
    for (int it = 0; it < 4; ++it) {
        int le = ly + it * 8;
        p1t[(size_t)(e0 + le) * HWB + h0 + lx] = tile[lx][le];
    }
}

// ---------------------------------------------------------------------------
// Prep C: conv_w [256][128][9] f32 -> wpack [256][tap*128+ci] bf16; zero zbuf
// ---------------------------------------------------------------------------
__global__ __launch_bounds__(256) void k_prep_w(
    const float* __restrict__ w, unsigned short* __restrict__ wp,
    float* __restrict__ zbuf)
{
    const int o = blockIdx.x, t = threadIdx.x;
#pragma unroll
    for (int k = t; k < 1152; k += 256) {
        int tap = k >> 7, ci = k & 127;
        wp[(size_t)o * 1152 + k] = f2bf(w[(size_t)o * 1152 + ci * 9 + tap]);
    }
    if (o == 0 && t < 64) zbuf[t] = 0.f;
}

// ---------------------------------------------------------------------------
// GEMM1: t4h[m][e] = bf16( (sum_hw x[m][hw] p1[hw][e]) * p4[m&255][e] )
// M=8192 K=3136 N=256. 128x128 tile, BK=32. A: f32->bf16 in-kernel staging.
// B via global_load_lds from p1t (k-contiguous).
// ---------------------------------------------------------------------------
__global__ __launch_bounds__(256) void k_gemm1(
    const float* __restrict__ x, const unsigned short* __restrict__ p1t,
    const float* __restrict__ p4, unsigned short* __restrict__ t4h)
{
    __shared__ short As[128 * 32];
    __shared__ short Bs[128 * 32];
    const int tid = threadIdx.x;
    const int tileM = blockIdx.y * 128;
    const int tileN = blockIdx.x * 128;
    const int wave = tid >> 6, lane = tid & 63;
    const int wm = (wave >> 1) * 64, wn = (wave & 1) * 64;

    const int ar = tid >> 3, aq = tid & 7;            // A: 4 passes of 32 rows
    const int br = tid >> 2, bq = tid & 3;            // B: 2 passes of 64 rows
    const unsigned short* bsrc = p1t + (size_t)(tileN + br) * HWB + bq * 8;
    short* bdst = &Bs[br * 32 + bq * 8];

    f32x4 acc[4][4] = {};
    const int frow = lane & 15, fk = (lane >> 4) * 8;

    for (int k0 = 0; k0 < HWB; k0 += 32) {
        __syncthreads();
        gl_lds16(bsrc + k0, bdst);
        gl_lds16(bsrc + (size_t)64 * HWB + k0, bdst + 64 * 32);
#pragma unroll
        for (int p = 0; p < 4; ++p) {
            int row = p * 32 + ar;
            float4 v = *(const float4*)&x[(size_t)(tileM + row) * HWB + k0 + aq * 4];
            unsigned lo = (unsigned)f2bf(v.x) | ((unsigned)f2bf(v.y) << 16);
            unsigned hi = (unsigned)f2bf(v.z) | ((unsigned)f2bf(v.w) << 16);
            *(uint2*)&As[row * 32 + aq * 4] = make_uint2(lo, hi);
        }
        __syncthreads();
        bf16x8 af[4], bf[4];
#pragma unroll
        for (int i = 0; i < 4; ++i)
            af[i] = *(const bf16x8*)&As[(wm + i * 16 + frow) * 32 + fk];
#pragma unroll
        for (int j = 0; j < 4; ++j)
            bf[j] = *(const bf16x8*)&Bs[(wn + j * 16 + frow) * 32 + fk];
#pragma unroll
        for (int i = 0; i < 4; ++i)
#pragma unroll
            for (int j = 0; j < 4; ++j)
                acc[i][j] = __builtin_amdgcn_mfma_f32_16x16x32_bf16(af[i], bf[j], acc[i][j], 0, 0, 0);
    }
#pragma unroll
    for (int j = 0; j < 4; ++j) {
        const int e = tileN + wn + j * 16 + (lane & 15);
#pragma unroll
        for (int i = 0; i < 4; ++i)
#pragma unroll
            for (int r = 0; r < 4; ++r) {
                int m = tileM + wm + i * 16 + (lane >> 4) * 4 + r;
                float v = acc[i][j][r] * p4[(size_t)(m & 255) * 256 + e];
                t4h[(size_t)m * 256 + e] = f2bf(v);
            }
    }
}

// ---------------------------------------------------------------------------
// t5[row] = sum_b t4h[row][b] * p5[b]
// ---------------------------------------------------------------------------
__global__ __launch_bounds__(256) void k_t5(
    const unsigned short* __restrict__ t4h, const float* __restrict__ p5,
    float* __restrict__ t5)
{
    const int row = blockIdx.x * 4 + (threadIdx.x >> 6);
    const int lane = threadIdx.x & 63;
    ushort4 a = *(const ushort4*)&t4h[(size_t)row * 256 + lane * 4];
    float4 b = *(const float4*)&p5[lane * 4];
    float sum = bf2f(a.x) * b.x + bf2f(a.y) * b.y + bf2f(a.z) * b.z + bf2f(a.w) * b.w;
#pragma unroll
    for (int off = 32; off > 0; off >>= 1) sum += __shfl_down(sum, off);
    if (lane == 0) t5[row] = sum;
}

// ---------------------------------------------------------------------------
// Conv (grouped 3x3) as MFMA GEMM per (n,g): D[m=s][n=o], K = 9 taps * 128 ci.
// A = im2col gathered from channels-last x_t via per-lane global_load_lds
// (OOB lanes read a zero buffer). B = wpack rows (k-contiguous).
// Output written channels-last: t3cl[n][s][c] bf16 (pad rows s>=3136 zeroed).
// ---------------------------------------------------------------------------
__global__ __launch_bounds__(256) void k_conv(
    const unsigned short* __restrict__ xt, const unsigned short* __restrict__ wp,
    const float* __restrict__ zbuf, unsigned short* __restrict__ t3cl)
{
    __shared__ short As[128 * 32];
    __shared__ short Bs[128 * 32];
    const int tid = threadIdx.x;
    const int n = blockIdx.y >> 1, g = blockIdx.y & 1;
    const int tileS = blockIdx.x * 128;
    const int wave = tid >> 6, lane = tid & 63;
    const int wm = (wave >> 1) * 64, wn = (wave & 1) * 64;

    const int ar = tid >> 2, aq = tid & 3;   // 2 passes of 64 rows, 4 chunks/row
    const unsigned short* bbase = wp + (size_t)(g * 128 + ar) * 1152 + aq * 8;
    short* bdst = &Bs[ar * 32 + aq * 8];
    short* adst = &As[ar * 32 + aq * 8];

    const unsigned short* xtn = xt + (size_t)n * HWB * 256 + g * 128 + aq * 8;
    const int sg0 = tileS + ar, sg1 = sg0 + 64;
    const int y0 = sg0 / 56, x0 = sg0 - y0 * 56;
    const int y1 = sg1 / 56, x1 = sg1 - y1 * 56;
    const bool vs0 = sg0 < HWB, vs1 = sg1 < HWB;
    const unsigned short* arow0 = xtn + (size_t)sg0 * 256;
    const unsigned short* arow1 = xtn + (size_t)sg1 * 256;

    f32x4 acc[4][4] = {};
    const int frow = lane & 15, fk = (lane >> 4) * 8;

    for (int k0 = 0; k0 < 1152; k0 += 32) {
        const int tap = k0 >> 7;
        const int dy = tap / 3 - 1, dx = tap - (tap / 3) * 3 - 1;
        const int kc = k0 & 127;
        const int shift = (dy * 56 + dx) * 256 + kc;
        __syncthreads();
        {
            bool v = vs0 && (unsigned)(y0 + dy) < 56u && (unsigned)(x0 + dx) < 56u;
            gl_lds16(v ? (const void*)(arow0 + shift) : (const void*)zbuf, adst);
        }
        {
            bool v = vs1 && (unsigned)(y1 + dy) < 56u && (unsigned)(x1 + dx) < 56u;
            gl_lds16(v ? (const void*)(arow1 + shift) : (const void*)zbuf, adst + 64 * 32);
        }
        gl_lds16(bbase + k0, bdst);
        gl_lds16(bbase + (size_t)64 * 1152 + k0, bdst + 64 * 32);
        __syncthreads();
        bf16x8 af[4], bf[4];
#pragma unroll
        for (int i = 0; i < 4; ++i)
            af[i] = *(const bf16x8*)&As[(wm + i * 16 + frow) * 32 + fk];
#pragma unroll
        for (int j = 0; j < 4; ++j)
            bf[j] = *(const bf16x8*)&Bs[(wn + j * 16 + frow) * 32 + fk];
#pragma unroll
        for (int i = 0; i < 4; ++i)
#pragma unroll
            for (int j = 0; j < 4; ++j)
                acc[i][j] = __builtin_amdgcn_mfma_f32_16x16x32_bf16(af[i], bf[j], acc[i][j], 0, 0, 0);
    }
    unsigned short* ob = t3cl + (size_t)n * HWPAD * 256 + g * 128;
#pragma unroll
    for (int i = 0; i < 4; ++i)
#pragma unroll
        for (int r = 0; r < 4; ++r) {
            int s = tileS + wm + i * 16 + (lane >> 4) * 4 + r;
            int c = wn + (lane & 15);
#pragma unroll
            for (int j = 0; j < 4; ++j) {
                float v = (s < HWB) ? acc[i][j][r] : 0.f;
                ob[(size_t)s * 256 + c + j * 16] = f2bf(v);
            }
        }
}

// ---------------------------------------------------------------------------
// t7[n][s] = (sum_c t5[n*256+c] * x[n][c][s]) / 16
// ---------------------------------------------------------------------------
__global__ __launch_bounds__(256) void k_t7(
    const float* __restrict__ x, const float* __restrict__ t5,
    float* __restrict__ t7)
{
    __shared__ float s5[256];
    const int n = blockIdx.y;
    s5[threadIdx.x] = t5[n * 256 + threadIdx.x];
    __syncthreads();
    const int s = blockIdx.x * 256 + threadIdx.x;
    if (s >= HWB) return;
    const float* xb = x + (size_t)n * 256 * HWB + s;
    float sum = 0.f;
#pragma unroll 8
    for (int c = 0; c < 256; ++c) sum += s5[c] * xb[(size_t)c * HWB];
    t7[n * HWB + s] = sum * 0.0625f;
}

// ---------------------------------------------------------------------------
// BMM: out[n][a][s] = (sum_b t4h[n][a][b] * t3cl[n][s][b]) / 16 + t7[n][s]
// D[m=a][n=s], K=256. A rows from t4h (k-contig), B^T rows from t3cl.
// ---------------------------------------------------------------------------
__global__ __launch_bounds__(256) void k_bmm(
    const unsigned short* __restrict__ t4h, const unsigned short* __restrict__ t3cl,
    const float* __restrict__ t7, float* __restrict__ out)
{
    __shared__ short As[128 * 32];
    __shared__ short Bs[128 * 32];
    const int tid = threadIdx.x;
    const int n = blockIdx.z;
    const int tileA = blockIdx.y * 128;
    const int tileS = blockIdx.x * 128;
    const int wave = tid >> 6, lane = tid & 63;
    const int wm = (wave >> 1) * 64, wn = (wave & 1) * 64;

    const int ar = tid >> 2, aq = tid & 3;
    const unsigned short* asrc = t4h + ((size_t)n * 256 + tileA + ar) * 256 + aq * 8;
    const unsigned short* bsrc = t3cl + ((size_t)n * HWPAD + tileS + ar) * 256 + aq * 8;
    short* adst = &As[ar * 32 + aq * 8];
    short* bdst = &Bs[ar * 32 + aq * 8];

    f32x4 acc[4][4] = {};
    const int frow = lane & 15, fk = (lane >> 4) * 8;

    for (int k0 = 0; k0 < 256; k0 += 32) {
        __syncthreads();
        gl_lds16(asrc + k0, adst);
        gl_lds16(asrc + 64 * 256 + k0, adst + 64 * 32);
        gl_lds16(bsrc + k0, bdst);
        gl_lds16(bsrc + 64 * 256 + k0, bdst + 64 * 32);
        __syncthreads();
        bf16x8 af[4], bf[4];
#pragma unroll
        for (int i = 0; i < 4; ++i)
            af[i] = *(const bf16x8*)&As[(wm + i * 16 + frow) * 32 + fk];
#pragma unroll
        for (int j = 0; j < 4; ++j)
            bf[j] = *(const bf16x8*)&Bs[(wn + j * 16 + frow) * 32 + fk];
#pragma unroll
        for (int i = 0; i < 4; ++i)
#pragma unroll
            for (int j = 0; j < 4; ++j)
                acc[i][j] = __builtin_amdgcn_mfma_f32_16x16x32_bf16(af[i], bf[j], acc[i][j], 0, 0, 0);
    }
    const float* t7n = t7 + (size_t)n * HWB;
    float* ob = out + (size_t)n * 256 * HWB;
#pragma unroll
    for (int j = 0; j < 4; ++j) {
        int s = tileS + wn + j * 16 + (lane & 15);
        bool vs = s < HWB;
        float t7v = vs ? t7n[s] : 0.f;
        if (!vs) continue;
#pragma unroll
        for (int i = 0; i < 4; ++i)
#pragma unroll
            for (int r = 0; r < 4; ++r) {
                int a = tileA + wm + i * 16 + (lane >> 4) * 4 + r;
                ob[(size_t)a * HWB + s] = acc[i][j][r] * 0.0625f + t7v;
            }
    }
}

extern "C" void kernel_launch(void* const* d_in, const int* in_sizes, int n_in,
                              void* d_out, int out_size, void* d_ws, size_t ws_size,
                              hipStream_t stream) {
    const float* x  = (const float*)d_in[0];
    const float* p1 = (const float*)d_in[1];
    const float* cw = (const float*)d_in[2];
    const float* p4 = (const float*)d_in[3];
    const float* p5 = (const float*)d_in[4];
    float* out = (float*)d_out;

    char* w = (char*)d_ws;
    unsigned short* xt    = (unsigned short*)w;               w += (size_t)32 * HWB * 256 * 2;
    unsigned short* t3cl  = (unsigned short*)w;               w += (size_t)32 * HWPAD * 256 * 2;
    unsigned short* p1t   = (unsigned short*)w;               w += (size_t)256 * HWB * 2;
    unsigned short* wpack = (unsigned short*)w;               w += (size_t)256 * 1152 * 2;
    unsigned short* t4h   = (unsigned short*)w;               w += (size_t)8192 * 256 * 2;
    float* t5             = (float*)w;                        w += (size_t)8192 * 4;
    float* t7             = (float*)w;                        w += (size_t)32 * HWB * 4;
    float* zbuf           = (float*)w;                        w += 256;

    k_prep_xt <<<dim3(98, 8, 32), 256, 0, stream>>>(x, xt);
    k_prep_p1t<<<dim3(98, 8),     256, 0, stream>>>(p1, p1t);
    k_prep_w  <<<dim3(256),       256, 0, stream>>>(cw, wpack, zbuf);
    k_gemm1   <<<dim3(2, 64),     256, 0, stream>>>(x, p1t, p4, t4h);
    k_t5      <<<dim3(2048),      256, 0, stream>>>(t4h, p5, t5);
    k_conv    <<<dim3(25, 64),    256, 0, stream>>>(xt, wpack, zbuf, t3cl);
    k_t7      <<<dim3(13, 32),    256, 0, stream>>>(x, t5, t7);
    k_bmm     <<<dim3(25, 2, 32), 256, 0, stream>>>(t4h, t3cl, t7, out);
}

// Round 3
// 421.352 us; speedup vs baseline: 3.3369x; 1.0775x over previous
//
#include <hip/hip_runtime.h>

#define HWB   3136
#define HWPAD 3200

typedef __attribute__((ext_vector_type(8))) short bf16x8;
typedef __attribute__((ext_vector_type(4))) float f32x4;

__device__ __forceinline__ unsigned short f2bf(float f) {
    unsigned u = __float_as_uint(f);
    unsigned r = (u + 0x7fffu + ((u >> 16) & 1u)) >> 16;
    return (unsigned short)r;
}
__device__ __forceinline__ float bf2f(unsigned short h) {
    return __uint_as_float(((unsigned)h) << 16);
}
__device__ __forceinline__ void gl_lds16(const void* g, void* l) {
    __builtin_amdgcn_global_load_lds(
        (const __attribute__((address_space(1))) void*)g,
        (__attribute__((address_space(3))) void*)l, 16, 0, 0);
}

// ---------------------------------------------------------------------------
// Prep A: x [32][256][3136] f32 -> x_t [32][3136][256] bf16 (channels-last)
// ---------------------------------------------------------------------------
__global__ __launch_bounds__(256) void k_prep_xt(
    const float* __restrict__ x, unsigned short* __restrict__ xt)
{
    __shared__ unsigned short tile[32][33];
    const int n = blockIdx.z, c0 = blockIdx.y * 32, s0 = blockIdx.x * 32;
    const int lx = threadIdx.x & 31, ly = threadIdx.x >> 5;
    const float* xb = x + ((size_t)(n * 256 + c0)) * HWB + s0;
#pragma unroll
    for (int it = 0; it < 4; ++it) {
        int lc = ly + it * 8;
        tile[lc][lx] = f2bf(xb[(size_t)lc * HWB + lx]);
    }
    __syncthreads();
    unsigned short* ob = xt + ((size_t)n * HWB + s0) * 256 + c0;
#pragma unroll
    for (int it = 0; it < 4; ++it) {
        int ls = ly + it * 8;
        ob[(size_t)ls * 256 + lx] = tile[lx][ls];
    }
}

// ---------------------------------------------------------------------------
// Prep B: p1 [3136][256] f32 -> p1t [256][3136] bf16
// ---------------------------------------------------------------------------
__global__ __launch_bounds__(256) void k_prep_p1t(
    const float* __restrict__ p1, unsigned short* __restrict__ p1t)
{
    __shared__ unsigned short tile[32][33];
    const int e0 = blockIdx.y * 32, h0 = blockIdx.x * 32;
    const int lx = threadIdx.x & 31, ly = threadIdx.x >> 5;
#pragma unroll
    for (int it = 0; it < 4; ++it) {
        int lh = ly + it * 8;
        tile[lh][lx] = f2bf(p1[(size_t)(h0 + lh) * 256 + e0 + lx]);
    }
    __syncthreads();
#pragma unroll
    for (int it = 0; it < 4; ++it) {
        int le = ly + it * 8;
        p1t[(size_t)(e0 + le) * HWB + h0 + lx] = tile[lx][le];
    }
}

// ---------------------------------------------------------------------------
// Prep C: conv_w [256][128][9] f32 -> wpack [256][tap*128+ci] bf16; zero zbuf
// ---------------------------------------------------------------------------
__global__ __launch_bounds__(256) void k_prep_w(
    const float* __restrict__ w, unsigned short* __restrict__ wp,
    float* __restrict__ zbuf)
{
    const int o = blockIdx.x, t = threadIdx.x;
#pragma unroll
    for (int k = t; k < 1152; k += 256) {
        int tap = k >> 7, ci = k & 127;
        wp[(size_t)o * 1152 + k] = f2bf(w[(size_t)o * 1152 + ci * 9 + tap]);
    }
    if (o == 0 && t < 64) zbuf[t] = 0.f;
}

// ---------------------------------------------------------------------------
// GEMM1 (split-K=7): t1acc[m][e] += sum_{k in chunk} x[m][k] p1t[e][k]
// M=8192 K=448/chunk N=256. 128x128 tile, BK=32. fp32 atomic accumulate.
// ---------------------------------------------------------------------------
__global__ __launch_bounds__(256) void k_gemm1(
    const float* __restrict__ x, const unsigned short* __restrict__ p1t,
    float* __restrict__ t1acc)
{
    __shared__ short As[128 * 32];
    __shared__ short Bs[128 * 32];
    const int tid = threadIdx.x;
    const int tileM = blockIdx.y * 128;
    const int tileN = blockIdx.x * 128;
    const int kbase = blockIdx.z * 448;
    const int wave = tid >> 6, lane = tid & 63;
    const int wm = (wave >> 1) * 64, wn = (wave & 1) * 64;

    const int ar = tid >> 3, aq = tid & 7;            // A: 4 passes of 32 rows
    const int br = tid >> 2, bq = tid & 3;            // B: 2 passes of 64 rows
    const unsigned short* bsrc = p1t + (size_t)(tileN + br) * HWB + bq * 8 + kbase;
    short* bdst = &Bs[br * 32 + bq * 8];

    f32x4 acc[4][4] = {};
    const int frow = lane & 15, fk = (lane >> 4) * 8;

    for (int k0 = 0; k0 < 448; k0 += 32) {
        __syncthreads();
        gl_lds16(bsrc + k0, bdst);
        gl_lds16(bsrc + (size_t)64 * HWB + k0, bdst + 64 * 32);
#pragma unroll
        for (int p = 0; p < 4; ++p) {
            int row = p * 32 + ar;
            float4 v = *(const float4*)&x[(size_t)(tileM + row) * HWB + kbase + k0 + aq * 4];
            unsigned lo = (unsigned)f2bf(v.x) | ((unsigned)f2bf(v.y) << 16);
            unsigned hi = (unsigned)f2bf(v.z) | ((unsigned)f2bf(v.w) << 16);
            *(uint2*)&As[row * 32 + aq * 4] = make_uint2(lo, hi);
        }
        __syncthreads();
        bf16x8 af[4], bf[4];
#pragma unroll
        for (int i = 0; i < 4; ++i)
            af[i] = *(const bf16x8*)&As[(wm + i * 16 + frow) * 32 + fk];
#pragma unroll
        for (int j = 0; j < 4; ++j)
            bf[j] = *(const bf16x8*)&Bs[(wn + j * 16 + frow) * 32 + fk];
#pragma unroll
        for (int i = 0; i < 4; ++i)
#pragma unroll
            for (int j = 0; j < 4; ++j)
                acc[i][j] = __builtin_amdgcn_mfma_f32_16x16x32_bf16(af[i], bf[j], acc[i][j], 0, 0, 0);
    }
#pragma unroll
    for (int j = 0; j < 4; ++j) {
        const int e = tileN + wn + j * 16 + (lane & 15);
#pragma unroll
        for (int i = 0; i < 4; ++i)
#pragma unroll
            for (int r = 0; r < 4; ++r) {
                int m = tileM + wm + i * 16 + (lane >> 4) * 4 + r;
                atomicAdd(&t1acc[(size_t)m * 256 + e], acc[i][j][r]);
            }
    }
}

// ---------------------------------------------------------------------------
// t4scale: t4h[m][e] = bf16(t1acc[m][e]*p4[m&255][e]); t5[m]=sum_e t4*p5[e]
// One wave per row.
// ---------------------------------------------------------------------------
__global__ __launch_bounds__(256) void k_t4scale(
    const float* __restrict__ t1acc, const float* __restrict__ p4,
    const float* __restrict__ p5, unsigned short* __restrict__ t4h,
    float* __restrict__ t5)
{
    const int row = blockIdx.x * 4 + (threadIdx.x >> 6);
    const int lane = threadIdx.x & 63;
    float4 a  = *(const float4*)&t1acc[(size_t)row * 256 + lane * 4];
    float4 sc = *(const float4*)&p4[(size_t)(row & 255) * 256 + lane * 4];
    float4 pv = *(const float4*)&p5[lane * 4];
    float v0 = a.x * sc.x, v1 = a.y * sc.y, v2 = a.z * sc.z, v3 = a.w * sc.w;
    ushort4 o;
    o.x = f2bf(v0); o.y = f2bf(v1); o.z = f2bf(v2); o.w = f2bf(v3);
    *(ushort4*)&t4h[(size_t)row * 256 + lane * 4] = o;
    float sum = v0 * pv.x + v1 * pv.y + v2 * pv.z + v3 * pv.w;
#pragma unroll
    for (int off = 32; off > 0; off >>= 1) sum += __shfl_down(sum, off);
    if (lane == 0) t5[row] = sum;
}

// ---------------------------------------------------------------------------
// Conv (grouped 3x3) as MFMA GEMM per (n,g): D[m=s][n=o], K = 9 taps * 128 ci.
// Output channels-last: t3cl[n][s][c] bf16.
// ---------------------------------------------------------------------------
__global__ __launch_bounds__(256) void k_conv(
    const unsigned short* __restrict__ xt, const unsigned short* __restrict__ wp,
    const float* __restrict__ zbuf, unsigned short* __restrict__ t3cl)
{
    __shared__ short As[128 * 32];
    __shared__ short Bs[128 * 32];
    const int tid = threadIdx.x;
    const int n = blockIdx.y >> 1, g = blockIdx.y & 1;
    const int tileS = blockIdx.x * 128;
    const int wave = tid >> 6, lane = tid & 63;
    const int wm = (wave >> 1) * 64, wn = (wave & 1) * 64;

    const int ar = tid >> 2, aq = tid & 3;
    const unsigned short* bbase = wp + (size_t)(g * 128 + ar) * 1152 + aq * 8;
    short* bdst = &Bs[ar * 32 + aq * 8];
    short* adst = &As[ar * 32 + aq * 8];

    const unsigned short* xtn = xt + (size_t)n * HWB * 256 + g * 128 + aq * 8;
    const int sg0 = tileS + ar, sg1 = sg0 + 64;
    const int y0 = sg0 / 56, x0 = sg0 - y0 * 56;
    const int y1 = sg1 / 56, x1 = sg1 - y1 * 56;
    const bool vs0 = sg0 < HWB, vs1 = sg1 < HWB;
    const unsigned short* arow0 = xtn + (size_t)sg0 * 256;
    const unsigned short* arow1 = xtn + (size_t)sg1 * 256;

    f32x4 acc[4][4] = {};
    const int frow = lane & 15, fk = (lane >> 4) * 8;

    for (int k0 = 0; k0 < 1152; k0 += 32) {
        const int tap = k0 >> 7;
        const int dy = tap / 3 - 1, dx = tap - (tap / 3) * 3 - 1;
        const int kc = k0 & 127;
        const int shift = (dy * 56 + dx) * 256 + kc;
        __syncthreads();
        {
            bool v = vs0 && (unsigned)(y0 + dy) < 56u && (unsigned)(x0 + dx) < 56u;
            gl_lds16(v ? (const void*)(arow0 + shift) : (const void*)zbuf, adst);
        }
        {
            bool v = vs1 && (unsigned)(y1 + dy) < 56u && (unsigned)(x1 + dx) < 56u;
            gl_lds16(v ? (const void*)(arow1 + shift) : (const void*)zbuf, adst + 64 * 32);
        }
        gl_lds16(bbase + k0, bdst);
        gl_lds16(bbase + (size_t)64 * 1152 + k0, bdst + 64 * 32);
        __syncthreads();
        bf16x8 af[4], bf[4];
#pragma unroll
        for (int i = 0; i < 4; ++i)
            af[i] = *(const bf16x8*)&As[(wm + i * 16 + frow) * 32 + fk];
#pragma unroll
        for (int j = 0; j < 4; ++j)
            bf[j] = *(const bf16x8*)&Bs[(wn + j * 16 + frow) * 32 + fk];
#pragma unroll
        for (int i = 0; i < 4; ++i)
#pragma unroll
            for (int j = 0; j < 4; ++j)
                acc[i][j] = __builtin_amdgcn_mfma_f32_16x16x32_bf16(af[i], bf[j], acc[i][j], 0, 0, 0);
    }
    unsigned short* ob = t3cl + (size_t)n * HWPAD * 256 + g * 128;
#pragma unroll
    for (int i = 0; i < 4; ++i)
#pragma unroll
        for (int r = 0; r < 4; ++r) {
            int s = tileS + wm + i * 16 + (lane >> 4) * 4 + r;
            int c = wn + (lane & 15);
#pragma unroll
            for (int j = 0; j < 4; ++j) {
                float v = (s < HWB) ? acc[i][j][r] : 0.f;
                ob[(size_t)s * 256 + c + j * 16] = f2bf(v);
            }
        }
}

// ---------------------------------------------------------------------------
// t7[n][s] = (sum_c t5[n*256+c] * xt[n][s][c]) / 16   (bf16 x, coalesced)
// One wave per 4 s-values; p5-side weights held in registers.
// ---------------------------------------------------------------------------
__global__ __launch_bounds__(256) void k_t7(
    const unsigned short* __restrict__ xt, const float* __restrict__ t5,
    float* __restrict__ t7)
{
    const int n = blockIdx.y;
    const int wave = threadIdx.x >> 6, lane = threadIdx.x & 63;
    float4 w = *(const float4*)&t5[n * 256 + lane * 4];
    const int s0 = blockIdx.x * 16 + wave * 4;
#pragma unroll
    for (int q = 0; q < 4; ++q) {
        const int s = s0 + q;
        ushort4 a = *(const ushort4*)&xt[((size_t)n * HWB + s) * 256 + lane * 4];
        float sum = bf2f(a.x) * w.x + bf2f(a.y) * w.y + bf2f(a.z) * w.z + bf2f(a.w) * w.w;
#pragma unroll
        for (int off = 32; off > 0; off >>= 1) sum += __shfl_down(sum, off);
        if (lane == 0) t7[n * HWB + s] = sum * 0.0625f;
    }
}

// ---------------------------------------------------------------------------
// BMM: out[n][a][s] = (sum_b t4h[n][a][b] * t3cl[n][s][b]) / 16 + t7[n][s]
// ---------------------------------------------------------------------------
__global__ __launch_bounds__(256) void k_bmm(
    const unsigned short* __restrict__ t4h, const unsigned short* __restrict__ t3cl,
    const float* __restrict__ t7, float* __restrict__ out)
{
    __shared__ short As[128 * 32];
    __shared__ short Bs[128 * 32];
    const int tid = threadIdx.x;
    const int n = blockIdx.z;
    const int tileA = blockIdx.y * 128;
    const int tileS = blockIdx.x * 128;
    const int wave = tid >> 6, lane = tid & 63;
    const int wm = (wave >> 1) * 64, wn = (wave & 1) * 64;

    const int ar = tid >> 2, aq = tid & 3;
    const unsigned short* asrc = t4h + ((size_t)n * 256 + tileA + ar) * 256 + aq * 8;
    const unsigned short* bsrc = t3cl + ((size_t)n * HWPAD + tileS + ar) * 256 + aq * 8;
    short* adst = &As[ar * 32 + aq * 8];
    short* bdst = &Bs[ar * 32 + aq * 8];

    f32x4 acc[4][4] = {};
    const int frow = lane & 15, fk = (lane >> 4) * 8;

    for (int k0 = 0; k0 < 256; k0 += 32) {
        __syncthreads();
        gl_lds16(asrc + k0, adst);
        gl_lds16(asrc + 64 * 256 + k0, adst + 64 * 32);
        gl_lds16(bsrc + k0, bdst);
        gl_lds16(bsrc + 64 * 256 + k0, bdst + 64 * 32);
        __syncthreads();
        bf16x8 af[4], bf[4];
#pragma unroll
        for (int i = 0; i < 4; ++i)
            af[i] = *(const bf16x8*)&As[(wm + i * 16 + frow) * 32 + fk];
#pragma unroll
        for (int j = 0; j < 4; ++j)
            bf[j] = *(const bf16x8*)&Bs[(wn + j * 16 + frow) * 32 + fk];
#pragma unroll
        for (int i = 0; i < 4; ++i)
#pragma unroll
            for (int j = 0; j < 4; ++j)
                acc[i][j] = __builtin_amdgcn_mfma_f32_16x16x32_bf16(af[i], bf[j], acc[i][j], 0, 0, 0);
    }
    const float* t7n = t7 + (size_t)n * HWB;
    float* ob = out + (size_t)n * 256 * HWB;
#pragma unroll
    for (int j = 0; j < 4; ++j) {
        int s = tileS + wn + j * 16 + (lane & 15);
        bool vs = s < HWB;
        float t7v = vs ? t7n[s] : 0.f;
        if (!vs) continue;
#pragma unroll
        for (int i = 0; i < 4; ++i)
#pragma unroll
            for (int r = 0; r < 4; ++r) {
                int a = tileA + wm + i * 16 + (lane >> 4) * 4 + r;
                ob[(size_t)a * HWB + s] = acc[i][j][r] * 0.0625f + t7v;
            }
    }
}

extern "C" void kernel_launch(void* const* d_in, const int* in_sizes, int n_in,
                              void* d_out, int out_size, void* d_ws, size_t ws_size,
                              hipStream_t stream) {
    const float* x  = (const float*)d_in[0];
    const float* p1 = (const float*)d_in[1];
    const float* cw = (const float*)d_in[2];
    const float* p4 = (const float*)d_in[3];
    const float* p5 = (const float*)d_in[4];
    float* out = (float*)d_out;

    char* w = (char*)d_ws;
    unsigned short* xt    = (unsigned short*)w;               w += (size_t)32 * HWB * 256 * 2;
    unsigned short* t3cl  = (unsigned short*)w;               w += (size_t)32 * HWPAD * 256 * 2;
    unsigned short* p1t   = (unsigned short*)w;               w += (size_t)256 * HWB * 2;
    unsigned short* wpack = (unsigned short*)w;               w += (size_t)256 * 1152 * 2;
    unsigned short* t4h   = (unsigned short*)w;               w += (size_t)8192 * 256 * 2;
    float* t1acc          = (float*)w;                        w += (size_t)8192 * 256 * 4;
    float* t5             = (float*)w;                        w += (size_t)8192 * 4;
    float* t7             = (float*)w;                        w += (size_t)32 * HWB * 4;
    float* zbuf           = (float*)w;                        w += 256;

    hipMemsetAsync(t1acc, 0, (size_t)8192 * 256 * 4, stream);
    k_prep_xt <<<dim3(98, 8, 32), 256, 0, stream>>>(x, xt);
    k_prep_p1t<<<dim3(98, 8),     256, 0, stream>>>(p1, p1t);
    k_prep_w  <<<dim3(256),       256, 0, stream>>>(cw, wpack, zbuf);
    k_conv    <<<dim3(25, 64),    256, 0, stream>>>(xt, wpack, zbuf, t3cl);
    k_gemm1   <<<dim3(2, 64, 7),  256, 0, stream>>>(x, p1t, t1acc);
    k_t4scale <<<dim3(2048),      256, 0, stream>>>(t1acc, p4, p5, t4h, t5);
    k_t7      <<<dim3(196, 32),   256, 0, stream>>>(xt, t5, t7);
    k_bmm     <<<dim3(25, 2, 32), 256, 0, stream>>>(t4h, t3cl, t7, out);
}

// Round 4
// 412.877 us; speedup vs baseline: 3.4054x; 1.0205x over previous
//
#include <hip/hip_runtime.h>

#define HWB   3136
#define HWPAD 3200

typedef __attribute__((ext_vector_type(8))) short bf16x8;
typedef __attribute__((ext_vector_type(4))) float f32x4;

__device__ __forceinline__ unsigned short f2bf(float f) {
    unsigned u = __float_as_uint(f);
    unsigned r = (u + 0x7fffu + ((u >> 16) & 1u)) >> 16;
    return (unsigned short)r;
}
__device__ __forceinline__ float bf2f(unsigned short h) {
    return __uint_as_float(((unsigned)h) << 16);
}
__device__ __forceinline__ void gl_lds16(const void* g, void* l) {
    __builtin_amdgcn_global_load_lds(
        (const __attribute__((address_space(1))) void*)g,
        (__attribute__((address_space(3))) void*)l, 16, 0, 0);
}

// ---------------------------------------------------------------------------
// Prep A: x [32][256][3136] f32 -> x_t [32][3136][256] bf16 (channels-last)
// ---------------------------------------------------------------------------
__global__ __launch_bounds__(256) void k_prep_xt(
    const float* __restrict__ x, unsigned short* __restrict__ xt)
{
    __shared__ unsigned short tile[32][33];
    const int n = blockIdx.z, c0 = blockIdx.y * 32, s0 = blockIdx.x * 32;
    const int lx = threadIdx.x & 31, ly = threadIdx.x >> 5;
    const float* xb = x + ((size_t)(n * 256 + c0)) * HWB + s0;
#pragma unroll
    for (int it = 0; it < 4; ++it) {
        int lc = ly + it * 8;
        tile[lc][lx] = f2bf(xb[(size_t)lc * HWB + lx]);
    }
    __syncthreads();
    unsigned short* ob = xt + ((size_t)n * HWB + s0) * 256 + c0;
#pragma unroll
    for (int it = 0; it < 4; ++it) {
        int ls = ly + it * 8;
        ob[(size_t)ls * 256 + lx] = tile[lx][ls];
    }
}

// ---------------------------------------------------------------------------
// Prep B: p1 [3136][256] f32 -> p1t [256][3136] bf16
// ---------------------------------------------------------------------------
__global__ __launch_bounds__(256) void k_prep_p1t(
    const float* __restrict__ p1, unsigned short* __restrict__ p1t)
{
    __shared__ unsigned short tile[32][33];
    const int e0 = blockIdx.y * 32, h0 = blockIdx.x * 32;
    const int lx = threadIdx.x & 31, ly = threadIdx.x >> 5;
#pragma unroll
    for (int it = 0; it < 4; ++it) {
        int lh = ly + it * 8;
        tile[lh][lx] = f2bf(p1[(size_t)(h0 + lh) * 256 + e0 + lx]);
    }
    __syncthreads();
#pragma unroll
    for (int it = 0; it < 4; ++it) {
        int le = ly + it * 8;
        p1t[(size_t)(e0 + le) * HWB + h0 + lx] = tile[lx][le];
    }
}

// ---------------------------------------------------------------------------
// Prep C: conv_w [256][128][9] f32 -> wpack [256][tap*128+ci] bf16; zero zbuf
// ---------------------------------------------------------------------------
__global__ __launch_bounds__(256) void k_prep_w(
    const float* __restrict__ w, unsigned short* __restrict__ wp,
    float* __restrict__ zbuf)
{
    const int o = blockIdx.x, t = threadIdx.x;
#pragma unroll
    for (int k = t; k < 1152; k += 256) {
        int tap = k >> 7, ci = k & 127;
        wp[(size_t)o * 1152 + k] = f2bf(w[(size_t)o * 1152 + ci * 9 + tap]);
    }
    if (o == 0 && t < 64) zbuf[t] = 0.f;
}

// ---------------------------------------------------------------------------
// GEMM1 (split-K=7, BK=64): t1acc[m][e] += sum_k x[m][k] p1t[e][k]
// A: fp32->bf16 VALU convert into padded LDS (stride 72, conflict-free reads).
// B: global_load_lds with XOR-swizzled chunks (stride 64).
// ---------------------------------------------------------------------------
__global__ __launch_bounds__(256) void k_gemm1(
    const float* __restrict__ x, const unsigned short* __restrict__ p1t,
    float* __restrict__ t1acc)
{
    __shared__ short As[128 * 72];
    __shared__ short Bs[128 * 64];
    const int tid = threadIdx.x;
    const int tileM = blockIdx.y * 128;
    const int tileN = blockIdx.x * 128;
    const int kbase = blockIdx.z * 448;
    const int wave = tid >> 6, lane = tid & 63;
    const int wm = (wave >> 1) * 64, wn = (wave & 1) * 64;

    const int rl = tid >> 3, q = tid & 7;       // 32 rows/pass, 8 chunks/row
    const int sw8 = rl & 7;
    const float* xbase = x + (size_t)(tileM + rl) * HWB + kbase + q * 8;
    const unsigned short* bbase = p1t + (size_t)(tileN + rl) * HWB + kbase + ((q ^ sw8) * 8);

    f32x4 acc[4][4] = {};
    const int frow = lane & 15, quad = lane >> 4, sw = frow & 15 & 7;

    for (int k0 = 0; k0 < 448; k0 += 64) {
        __syncthreads();
#pragma unroll
        for (int p = 0; p < 4; ++p)
            gl_lds16(bbase + (size_t)(p * 32) * HWB + k0, &Bs[(p * 32 + rl) * 64 + q * 8]);
#pragma unroll
        for (int p = 0; p < 4; ++p) {
            float4 v0 = *(const float4*)(xbase + (size_t)(p * 32) * HWB + k0);
            float4 v1 = *(const float4*)(xbase + (size_t)(p * 32) * HWB + k0 + 4);
            uint4 pk;
            pk.x = (unsigned)f2bf(v0.x) | ((unsigned)f2bf(v0.y) << 16);
            pk.y = (unsigned)f2bf(v0.z) | ((unsigned)f2bf(v0.w) << 16);
            pk.z = (unsigned)f2bf(v1.x) | ((unsigned)f2bf(v1.y) << 16);
            pk.w = (unsigned)f2bf(v1.z) | ((unsigned)f2bf(v1.w) << 16);
            *(uint4*)&As[(p * 32 + rl) * 72 + q * 8] = pk;
        }
        __syncthreads();
#pragma unroll
        for (int h = 0; h < 2; ++h) {
            bf16x8 af[4], bf[4];
#pragma unroll
            for (int i = 0; i < 4; ++i)
                af[i] = *(const bf16x8*)&As[(wm + i * 16 + frow) * 72 + h * 32 + quad * 8];
#pragma unroll
            for (int j = 0; j < 4; ++j)
                bf[j] = *(const bf16x8*)&Bs[(wn + j * 16 + frow) * 64 + ((h * 4 + quad) ^ sw) * 8];
#pragma unroll
            for (int i = 0; i < 4; ++i)
#pragma unroll
                for (int j = 0; j < 4; ++j)
                    acc[i][j] = __builtin_amdgcn_mfma_f32_16x16x32_bf16(af[i], bf[j], acc[i][j], 0, 0, 0);
        }
    }
#pragma unroll
    for (int j = 0; j < 4; ++j) {
        const int e = tileN + wn + j * 16 + (lane & 15);
#pragma unroll
        for (int i = 0; i < 4; ++i)
#pragma unroll
            for (int r = 0; r < 4; ++r) {
                int m = tileM + wm + i * 16 + (lane >> 4) * 4 + r;
                atomicAdd(&t1acc[(size_t)m * 256 + e], acc[i][j][r]);
            }
    }
}

// ---------------------------------------------------------------------------
// t4scale: t4h[m][e] = bf16(t1acc[m][e]*p4[m&255][e]); t5[m]=sum_e t4*p5[e]
// ---------------------------------------------------------------------------
__global__ __launch_bounds__(256) void k_t4scale(
    const float* __restrict__ t1acc, const float* __restrict__ p4,
    const float* __restrict__ p5, unsigned short* __restrict__ t4h,
    float* __restrict__ t5)
{
    const int row = blockIdx.x * 4 + (threadIdx.x >> 6);
    const int lane = threadIdx.x & 63;
    float4 a  = *(const float4*)&t1acc[(size_t)row * 256 + lane * 4];
    float4 sc = *(const float4*)&p4[(size_t)(row & 255) * 256 + lane * 4];
    float4 pv = *(const float4*)&p5[lane * 4];
    float v0 = a.x * sc.x, v1 = a.y * sc.y, v2 = a.z * sc.z, v3 = a.w * sc.w;
    ushort4 o;
    o.x = f2bf(v0); o.y = f2bf(v1); o.z = f2bf(v2); o.w = f2bf(v3);
    *(ushort4*)&t4h[(size_t)row * 256 + lane * 4] = o;
    float sum = v0 * pv.x + v1 * pv.y + v2 * pv.z + v3 * pv.w;
#pragma unroll
    for (int off = 32; off > 0; off >>= 1) sum += __shfl_down(sum, off);
    if (lane == 0) t5[row] = sum;
}

// ---------------------------------------------------------------------------
// Conv (grouped 3x3) MFMA GEMM per (n,g): D[m=s][n=o], K = 9 taps * 128 ci.
// BK=64, XOR-swizzled LDS chunks for conflict-free b128 frag reads.
// Output channels-last: t3cl[n][s][c] bf16 (pad rows zeroed).
// ---------------------------------------------------------------------------
__global__ __launch_bounds__(256) void k_conv(
    const unsigned short* __restrict__ xt, const unsigned short* __restrict__ wp,
    const float* __restrict__ zbuf, unsigned short* __restrict__ t3cl)
{
    __shared__ short As[128 * 64];
    __shared__ short Bs[128 * 64];
    const int tid = threadIdx.x;
    const int n = blockIdx.y >> 1, g = blockIdx.y & 1;
    const int tileS = blockIdx.x * 128;
    const int wave = tid >> 6, lane = tid & 63;
    const int wm = (wave >> 1) * 64, wn = (wave & 1) * 64;

    const int rl = tid >> 3, q = tid & 7;
    const int swq = (q ^ (rl & 7)) * 8;     // swizzled source chunk (shorts)

    const unsigned short* xtn = xt + (size_t)n * HWB * 256 + g * 128;
    const unsigned short* arow[4];
    const unsigned short* brow[4];
    int yy[4], xx[4];
    bool vs[4];
#pragma unroll
    for (int p = 0; p < 4; ++p) {
        int s = tileS + p * 32 + rl;
        yy[p] = s / 56; xx[p] = s - yy[p] * 56;
        vs[p] = s < HWB;
        arow[p] = xtn + (size_t)s * 256 + swq;
        brow[p] = wp + (size_t)(g * 128 + p * 32 + rl) * 1152 + swq;
    }

    f32x4 acc[4][4] = {};
    const int frow = lane & 15, quad = lane >> 4, sw = frow & 7;
    int rofA[4], rofB[4];
#pragma unroll
    for (int i = 0; i < 4; ++i) {
        rofA[i] = (wm + i * 16 + frow) * 64;
        rofB[i] = (wn + i * 16 + frow) * 64;
    }

    for (int k0 = 0; k0 < 1152; k0 += 64) {
        const int tap = k0 >> 7;
        const int dy = tap / 3 - 1, dx = tap - (tap / 3) * 3 - 1;
        const int kc = k0 & 127;
        const int shift = (dy * 56 + dx) * 256 + kc;
        __syncthreads();
#pragma unroll
        for (int p = 0; p < 4; ++p) {
            bool v = vs[p] && (unsigned)(yy[p] + dy) < 56u && (unsigned)(xx[p] + dx) < 56u;
            gl_lds16(v ? (const void*)(arow[p] + shift) : (const void*)zbuf,
                     &As[(p * 32 + rl) * 64 + q * 8]);
            gl_lds16(brow[p] + k0, &Bs[(p * 32 + rl) * 64 + q * 8]);
        }
        __syncthreads();
#pragma unroll
        for (int h = 0; h < 2; ++h) {
            bf16x8 af[4], bf[4];
#pragma unroll
            for (int i = 0; i < 4; ++i)
                af[i] = *(const bf16x8*)&As[rofA[i] + ((h * 4 + quad) ^ sw) * 8];
#pragma unroll
            for (int j = 0; j < 4; ++j)
                bf[j] = *(const bf16x8*)&Bs[rofB[j] + ((h * 4 + quad) ^ sw) * 8];
#pragma unroll
            for (int i = 0; i < 4; ++i)
#pragma unroll
                for (int j = 0; j < 4; ++j)
                    acc[i][j] = __builtin_amdgcn_mfma_f32_16x16x32_bf16(af[i], bf[j], acc[i][j], 0, 0, 0);
        }
    }
    unsigned short* ob = t3cl + (size_t)n * HWPAD * 256 + g * 128;
#pragma unroll
    for (int i = 0; i < 4; ++i)
#pragma unroll
        for (int r = 0; r < 4; ++r) {
            int s = tileS + wm + i * 16 + (lane >> 4) * 4 + r;
            int c = wn + (lane & 15);
#pragma unroll
            for (int j = 0; j < 4; ++j) {
                float v = (s < HWB) ? acc[i][j][r] : 0.f;
                ob[(size_t)s * 256 + c + j * 16] = f2bf(v);
            }
        }
}

// ---------------------------------------------------------------------------
// t7[n][s] = (sum_c t5[n*256+c] * xt[n][s][c]) / 16   (bf16 x, coalesced)
// ---------------------------------------------------------------------------
__global__ __launch_bounds__(256) void k_t7(
    const unsigned short* __restrict__ xt, const float* __restrict__ t5,
    float* __restrict__ t7)
{
    const int n = blockIdx.y;
    const int wave = threadIdx.x >> 6, lane = threadIdx.x & 63;
    float4 w = *(const float4*)&t5[n * 256 + lane * 4];
    const int s0 = blockIdx.x * 16 + wave * 4;
#pragma unroll
    for (int q = 0; q < 4; ++q) {
        const int s = s0 + q;
        ushort4 a = *(const ushort4*)&xt[((size_t)n * HWB + s) * 256 + lane * 4];
        float sum = bf2f(a.x) * w.x + bf2f(a.y) * w.y + bf2f(a.z) * w.z + bf2f(a.w) * w.w;
#pragma unroll
        for (int off = 32; off > 0; off >>= 1) sum += __shfl_down(sum, off);
        if (lane == 0) t7[n * HWB + s] = sum * 0.0625f;
    }
}

// ---------------------------------------------------------------------------
// BMM: out[n][a][s] = (sum_b t4h[n][a][b] * t3cl[n][s][b]) / 16 + t7[n][s]
// BK=64, swizzled staging, 4 K-iterations.
// ---------------------------------------------------------------------------
__global__ __launch_bounds__(256) void k_bmm(
    const unsigned short* __restrict__ t4h, const unsigned short* __restrict__ t3cl,
    const float* __restrict__ t7, float* __restrict__ out)
{
    __shared__ short As[128 * 64];
    __shared__ short Bs[128 * 64];
    const int tid = threadIdx.x;
    const int n = blockIdx.z;
    const int tileA = blockIdx.y * 128;
    const int tileS = blockIdx.x * 128;
    const int wave = tid >> 6, lane = tid & 63;
    const int wm = (wave >> 1) * 64, wn = (wave & 1) * 64;

    const int rl = tid >> 3, q = tid & 7;
    const int swq = (q ^ (rl & 7)) * 8;
    const unsigned short* asrc = t4h + ((size_t)n * 256 + tileA + rl) * 256 + swq;
    const unsigned short* bsrc = t3cl + ((size_t)n * HWPAD + tileS + rl) * 256 + swq;

    f32x4 acc[4][4] = {};
    const int frow = lane & 15, quad = lane >> 4, sw = frow & 7;

    for (int k0 = 0; k0 < 256; k0 += 64) {
        __syncthreads();
#pragma unroll
        for (int p = 0; p < 4; ++p) {
            gl_lds16(asrc + (size_t)(p * 32) * 256 + k0, &As[(p * 32 + rl) * 64 + q * 8]);
            gl_lds16(bsrc + (size_t)(p * 32) * 256 + k0, &Bs[(p * 32 + rl) * 64 + q * 8]);
        }
        __syncthreads();
#pragma unroll
        for (int h = 0; h < 2; ++h) {
            bf16x8 af[4], bf[4];
#pragma unroll
            for (int i = 0; i < 4; ++i)
                af[i] = *(const bf16x8*)&As[(wm + i * 16 + frow) * 64 + ((h * 4 + quad) ^ sw) * 8];
#pragma unroll
            for (int j = 0; j < 4; ++j)
                bf[j] = *(const bf16x8*)&Bs[(wn + j * 16 + frow) * 64 + ((h * 4 + quad) ^ sw) * 8];
#pragma unroll
            for (int i = 0; i < 4; ++i)
#pragma unroll
                for (int j = 0; j < 4; ++j)
                    acc[i][j] = __builtin_amdgcn_mfma_f32_16x16x32_bf16(af[i], bf[j], acc[i][j], 0, 0, 0);
        }
    }
    const float* t7n = t7 + (size_t)n * HWB;
    float* ob = out + (size_t)n * 256 * HWB;
#pragma unroll
    for (int j = 0; j < 4; ++j) {
        int s = tileS + wn + j * 16 + (lane & 15);
        bool vsx = s < HWB;
        float t7v = vsx ? t7n[s] : 0.f;
        if (!vsx) continue;
#pragma unroll
        for (int i = 0; i < 4; ++i)
#pragma unroll
            for (int r = 0; r < 4; ++r) {
                int a = tileA + wm + i * 16 + (lane >> 4) * 4 + r;
                ob[(size_t)a * HWB + s] = acc[i][j][r] * 0.0625f + t7v;
            }
    }
}

extern "C" void kernel_launch(void* const* d_in, const int* in_sizes, int n_in,
                              void* d_out, int out_size, void* d_ws, size_t ws_size,
                              hipStream_t stream) {
    const float* x  = (const float*)d_in[0];
    const float* p1 = (const float*)d_in[1];
    const float* cw = (const float*)d_in[2];
    const float* p4 = (const float*)d_in[3];
    const float* p5 = (const float*)d_in[4];
    float* out = (float*)d_out;

    char* w = (char*)d_ws;
    unsigned short* xt    = (unsigned short*)w;               w += (size_t)32 * HWB * 256 * 2;
    unsigned short* t3cl  = (unsigned short*)w;               w += (size_t)32 * HWPAD * 256 * 2;
    unsigned short* p1t   = (unsigned short*)w;               w += (size_t)256 * HWB * 2;
    unsigned short* wpack = (unsigned short*)w;               w += (size_t)256 * 1152 * 2;
    unsigned short* t4h   = (unsigned short*)w;               w += (size_t)8192 * 256 * 2;
    float* t1acc          = (float*)w;                        w += (size_t)8192 * 256 * 4;
    float* t5             = (float*)w;                        w += (size_t)8192 * 4;
    float* t7             = (float*)w;                        w += (size_t)32 * HWB * 4;
    float* zbuf           = (float*)w;                        w += 256;

    hipMemsetAsync(t1acc, 0, (size_t)8192 * 256 * 4, stream);
    k_prep_xt <<<dim3(98, 8, 32), 256, 0, stream>>>(x, xt);
    k_prep_p1t<<<dim3(98, 8),     256, 0, stream>>>(p1, p1t);
    k_prep_w  <<<dim3(256),       256, 0, stream>>>(cw, wpack, zbuf);
    k_conv    <<<dim3(25, 64),    256, 0, stream>>>(xt, wpack, zbuf, t3cl);
    k_gemm1   <<<dim3(2, 64, 7),  256, 0, stream>>>(x, p1t, t1acc);
    k_t4scale <<<dim3(2048),      256, 0, stream>>>(t1acc, p4, p5, t4h, t5);
    k_t7      <<<dim3(196, 32),   256, 0, stream>>>(xt, t5, t7);
    k_bmm     <<<dim3(25, 2, 32), 256, 0, stream>>>(t4h, t3cl, t7, out);
}